// Round 8
// baseline (71.339 us; speedup 1.0000x reference)
//
#include <hip/hip_runtime.h>
#include <hip/hip_bf16.h>

typedef __attribute__((ext_vector_type(8))) short bf16x8;
typedef __attribute__((ext_vector_type(4))) float f32x4;
typedef __attribute__((ext_vector_type(4))) int   i32x4;
typedef __attribute__((ext_vector_type(2))) int   i32x2;

#define DEV static __device__ __forceinline__

DEV unsigned short f2bf(float f) {
  __hip_bfloat16 h = __float2bfloat16(f);
  return __builtin_bit_cast(unsigned short, h);
}
DEV int pack2(float a, float b) {
  return (int)f2bf(a) | ((int)f2bf(b) << 16);
}
DEV bf16x8 ldsFrag(const char* lds, int off) {
  i32x4 v = *(const i32x4*)(lds + off);
  return __builtin_bit_cast(bf16x8, v);
}

// Tiled operand layout: each 1KB tile = one MFMA fragment set for a full wave,
// element order = lane-linear (lane l's 16B at tile_base + l*16B).
// A-frag tile [16 rows][32 k]: lane l -> (row = l&15, k = (l>>4)*8 + j)
// B-frag tile [16 cols][32 k]: identical order.

// ---------------- pre-kernel ----------------
__global__ __launch_bounds__(256) void cvt_all(
    const float* __restrict__ x, unsigned short* __restrict__ xt,
    const float* __restrict__ sw, unsigned short* __restrict__ swb,
    const float* __restrict__ tw, unsigned short* __restrict__ twb)
{
  const int bid = blockIdx.x;
  const int tid = threadIdx.x;
  if (bid < 512) {
    __shared__ unsigned short lt[64][72];
    const int ut = bid & 3;          // u group of 64
    const int mt = (bid >> 2) & 7;   // m group of 64
    const int bc = bid >> 5;         // 0..15
    const int ul = tid & 63;
    const int mr = tid >> 6;
    const float* px = x + ((size_t)bc * 512 + mt * 64) * 256 + ut * 64;
#pragma unroll
    for (int r = 0; r < 16; r++) {
      int m = r * 4 + mr;
      lt[m][ul] = f2bf(px[(size_t)m * 256 + ul]);
    }
    __syncthreads();
    const int t8 = tid >> 5;
    const int a  = t8 & 3;
    const int bb = t8 >> 2;
    const int l0 = tid & 31;
    unsigned short* tilep =
        xt + (((size_t)(bc * 16 + ut * 4 + a)) * 16 + (mt * 2 + bb)) * 512;
#pragma unroll
    for (int h = 0; h < 2; h++) {
      int l = l0 + h * 32;
      int ur = a * 16 + (l & 15);
      int mb = bb * 32 + (l >> 4) * 8;
      i32x4 w;
#pragma unroll
      for (int j = 0; j < 4; j++)
        w[j] = (int)lt[mb + 2 * j][ur] | ((int)lt[mb + 2 * j + 1][ur] << 16);
      *(i32x4*)(tilep + l * 8) = w;
    }
  } else if (bid < 1024) {
    const int tile = (bid - 512) * 4 + (tid >> 6);
    const int l = tid & 63;
    const int mt2 = tile & 15;
    const int nt2 = (tile >> 4) & 31;
    const int p   = tile >> 9;
    const float* ps = sw + ((size_t)p * 512 + nt2 * 16 + (l & 15)) * 512
                         + mt2 * 32 + (l >> 4) * 8;
    f32x4 A = ((const f32x4*)ps)[0], Bv = ((const f32x4*)ps)[1];
    i32x4 w;
    w[0] = pack2(A[0], A[1]);  w[1] = pack2(A[2], A[3]);
    w[2] = pack2(Bv[0], Bv[1]); w[3] = pack2(Bv[2], Bv[3]);
    *(i32x4*)(swb + (size_t)tile * 512 + l * 8) = w;
  } else {
    const int tile = (bid - 1024) * 4 + (tid >> 6);
    const int l = tid & 63;
    const int ut2 = tile & 7;
    const int tt2 = (tile >> 3) & 15;
    const int q   = tile >> 7;
    const float* pt = tw + ((size_t)q * 256 + tt2 * 16 + (l & 15)) * 256
                         + ut2 * 32 + (l >> 4) * 8;
    f32x4 A = ((const f32x4*)pt)[0], Bv = ((const f32x4*)pt)[1];
    i32x4 w;
    w[0] = pack2(A[0], A[1]);  w[1] = pack2(A[2], A[3]);
    w[2] = pack2(Bv[0], Bv[1]); w[3] = pack2(Bv[2], Bv[3]);
    *(i32x4*)(twb + (size_t)tile * 512 + l * 8) = w;
  }
}

// ---------------- main fused kernel ----------------
// B=4, C=4, N=512, T=256, K(P)=4, J(Q)=4
// Block = (bc, p, n-tile of 64). Grid 512, 512 threads.
// Stage A: tmp[n][u] = sum_m S_p[n0+n][m]*X[m][u] (acc = tmp^T frags; tiled loads)
//   -> tmp in LDS, then HOISTED to registers (afr[8][2]).
// Stage B: 16 phases (q,tc), visited in per-block ROTATED order (bx&15) so that
//   concurrent blocks spread their 256B-per-1KB store pattern across all memory
//   channels instead of lockstepping on the same tc (mod 4) channel group.
__global__ __launch_bounds__(512, 4) void stblis_main(
    const unsigned short* __restrict__ xt, const unsigned short* __restrict__ swb,
    const unsigned short* __restrict__ twb, float* __restrict__ out)
{
  // LDS: phase 1: tmp[n=64][u=256] bf16, row 512B, slot s=(u>>3)^(n&7)  [0,32768)
  //      phase 2: stg0 [0,16384), stg1 [16384,32768):
  //               y f32 [64 n][16 chunks of 16B], chunk c at (c^(n&7))*16
  __shared__ __align__(16) char lds[32768];

  const int tid  = threadIdx.x;
  const int lane = tid & 63;
  const int wid  = tid >> 6;
  const int l15  = lane & 15;
  const int l4   = lane >> 4;

  const int bx = blockIdx.x;
  const int nt = bx & 7;          // n-tile of 64
  const int p  = (bx >> 3) & 3;
  const int bc = bx >> 5;         // b*4 + c
  const int n0 = nt * 64;
  const int b = bc >> 2, c = bc & 3;

  // ---------------- stage A ----------------
  const int wu = wid >> 1;   // u block of 64
  const int wn = wid & 1;    // n block of 32

  f32x4 acc[4][2];
#pragma unroll
  for (int i = 0; i < 4; i++)
#pragma unroll
    for (int j = 0; j < 2; j++) acc[i][j] = {0.f, 0.f, 0.f, 0.f};

  const unsigned short* xA = xt  + (((size_t)(bc * 16 + wu * 4)) * 16) * 512 + lane * 8;
  const unsigned short* sB = swb + (((size_t)(p * 32 + nt * 4 + wn * 2)) * 16) * 512 + lane * 8;

  for (int kc = 0; kc < 8; kc++) {
#pragma unroll
    for (int ks = 0; ks < 2; ks++) {
      const int mt2 = kc * 2 + ks;
      bf16x8 af[4], bg[2];
#pragma unroll
      for (int uf = 0; uf < 4; uf++)
        af[uf] = *(const bf16x8*)(xA + ((size_t)uf * 16 + mt2) * 512);
#pragma unroll
      for (int nf = 0; nf < 2; nf++)
        bg[nf] = *(const bf16x8*)(sB + ((size_t)nf * 16 + mt2) * 512);
#pragma unroll
      for (int uf = 0; uf < 4; uf++)
#pragma unroll
        for (int nf = 0; nf < 2; nf++)
          acc[uf][nf] = __builtin_amdgcn_mfma_f32_16x16x32_bf16(
              af[uf], bg[nf], acc[uf][nf], 0, 0, 0);
    }
  }

  // acc (tmp^T frags: row=u, col=n) -> LDS tmp[n][u] bf16 (swizzled)
#pragma unroll
  for (int uf = 0; uf < 4; uf++)
#pragma unroll
    for (int nf = 0; nf < 2; nf++) {
      int u0 = wu * 64 + uf * 16 + l4 * 4;
      int n  = wn * 32 + nf * 16 + l15;
      i32x2 w;
      w[0] = pack2(acc[uf][nf][0], acc[uf][nf][1]);
      w[1] = pack2(acc[uf][nf][2], acc[uf][nf][3]);
      *(i32x2*)(lds + n * 512 + (((u0 >> 3) ^ (n & 7)) << 4) + (u0 & 7) * 2) = w;
    }
  __syncthreads();

  // ---------------- stage B ----------------
  const int tq = wid >> 1;       // t quarter (16 t)
  const int nh = wid & 1;        // n half (32 n)
  const int phOff = bx & 15;     // per-block phase rotation (channel spreading)

#define LOADBG(dst, ph)                                                        \
  {                                                                            \
    const int q_ = (ph) >> 2, tc_ = (ph) & 3;                                  \
    const unsigned short* tA_ =                                                \
        twb + (((size_t)(q_ * 16 + tc_ * 4 + tq)) * 8) * 512 + lane * 8;       \
    _Pragma("unroll")                                                          \
    for (int us = 0; us < 8; us++)                                             \
      dst[us] = *(const bf16x8*)(tA_ + (size_t)us * 512);                      \
  }

  // prefetch first logical phase's bg (global, overlaps the hoist ds_reads)
  bf16x8 bgA[8], bgB[8];
  LOADBG(bgA, phOff);

  // hoist tmp A-frags to registers: phase-invariant
  bf16x8 afr[8][2];
#pragma unroll
  for (int us = 0; us < 8; us++)
#pragma unroll
    for (int nf = 0; nf < 2; nf++) {
      int n = nh * 32 + nf * 16 + l15;
      afr[us][nf] = ldsFrag(lds, n * 512 + (((us * 4 + l4) ^ (n & 7)) << 4));
    }
  __syncthreads();   // tmp now dead; staging buffers alias it

  char* const stg0 = lds;
  char* const stg1 = lds + 16384;

  auto body = [&](int ph, bf16x8 (&bg)[8], char* stgW) {
    const int q  = ph >> 2;
    const int tc = ph & 3;
    f32x4 a2[2];
    a2[0] = {0.f, 0.f, 0.f, 0.f};
    a2[1] = {0.f, 0.f, 0.f, 0.f};
#pragma unroll
    for (int us = 0; us < 8; us++) {
      a2[0] = __builtin_amdgcn_mfma_f32_16x16x32_bf16(bg[us], afr[us][0], a2[0], 0, 0, 0);
      a2[1] = __builtin_amdgcn_mfma_f32_16x16x32_bf16(bg[us], afr[us][1], a2[1], 0, 0, 0);
    }
    // stage y-frags to LDS: lane's 4 regs = 4 consecutive t -> one 16B chunk
#pragma unroll
    for (int nf = 0; nf < 2; nf++) {
      int n = nh * 32 + nf * 16 + l15;
      int c16 = tq * 4 + l4;
      *(f32x4*)(stgW + n * 256 + ((c16 ^ (n & 7)) << 4)) = a2[nf];
    }
    __syncthreads();
    // linear store: lanes 0..15 cover a full 256B row (2 full 128B lines)
    float* outQP = out + ((size_t)(b * 128 + c * 16 + p * 4 + q) * 512 + n0) * 256;
    float* outQN = outQP + (size_t)64 * 512 * 256;
#pragma unroll
    for (int h = 0; h < 2; h++) {
      int cc  = tid + h * 512;
      int r   = cc >> 4;
      int o16 = cc & 15;
      f32x4 y = *(const f32x4*)(stgW + r * 256 + ((o16 ^ (r & 7)) << 4));
      f32x4 vP, vN;
#pragma unroll
      for (int j = 0; j < 4; j++) {
        vP[j] = fmaxf(y[j], 0.f);
        vN[j] = fmaxf(-y[j], 0.f);
      }
      size_t go = (size_t)r * 256 + tc * 64 + o16 * 4;
      *(f32x4*)(outQP + go) = vP;
      *(f32x4*)(outQN + go) = vN;
    }
    // WAR on stgW (logical phase l+2's writes) is fenced by l+1's barrier
  };

  for (int l2 = 0; l2 < 8; l2++) {
    const int l = l2 * 2;
    LOADBG(bgB, (l + 1 + phOff) & 15);           // prefetch hides under body
    body((l + phOff) & 15, bgA, stg0);
    if (l2 < 7) LOADBG(bgA, (l + 2 + phOff) & 15);
    body((l + 1 + phOff) & 15, bgB, stg1);
  }
#undef LOADBG
}

extern "C" void kernel_launch(void* const* d_in, const int* in_sizes, int n_in,
                              void* d_out, int out_size, void* d_ws, size_t ws_size,
                              hipStream_t stream) {
  (void)in_sizes; (void)n_in; (void)out_size; (void)ws_size;
  const float* x  = (const float*)d_in[0];
  const float* sw = (const float*)d_in[1];
  const float* tw = (const float*)d_in[2];
  float* out = (float*)d_out;

  // workspace (u16 elements): xt 16*16*16*512 (4 MB) | swb 2048*512 (2 MB) | twb 512*512 (0.5 MB)
  unsigned short* xt  = (unsigned short*)d_ws;
  unsigned short* swb = xt + (size_t)16 * 16 * 16 * 512;
  unsigned short* twb = swb + (size_t)2048 * 512;

  cvt_all<<<dim3(1152), dim3(256), 0, stream>>>(x, xt, sw, swb, tw, twb);
  stblis_main<<<dim3(512), dim3(512), 0, stream>>>(xt, swb, twb, out);
}